// Round 1
// baseline (15.722 us; speedup 1.0000x reference)
//
#include <hip/hip_runtime.h>

// Live computation of the reference (everything else is dead code):
//   inpt[384] = concat(x[64], prev_output[64], state[256])
//   h1[1024]  = relu(w1_0 @ inpt + b1_0)   w1_0: (1024,384) row-major
//   h2[1024]  = relu(w1_1 @ h1   + b1_1)   w1_1: (1024,1024)
//   out[64]   = relu(w1_2 @ h2   + b1_2)   w1_2: (64,1024)

__device__ __forceinline__ float wave_reduce_sum(float v) {
    // 64-lane wave on gfx950
    v += __shfl_xor(v, 32, 64);
    v += __shfl_xor(v, 16, 64);
    v += __shfl_xor(v, 8, 64);
    v += __shfl_xor(v, 4, 64);
    v += __shfl_xor(v, 2, 64);
    v += __shfl_xor(v, 1, 64);
    return v;
}

// Layer 1: input is the concatenation of three source vectors. K = 384.
// 256 threads/block = 4 waves -> 4 rows per block. 256 blocks for 1024 rows.
__global__ void __launch_bounds__(256) fc_relu_concat(
        const float* __restrict__ x, const float* __restrict__ po,
        const float* __restrict__ st,
        const float* __restrict__ w, const float* __restrict__ b,
        float* __restrict__ out) {
    __shared__ float s_in[384];
    const int t = threadIdx.x;
    for (int i = t; i < 384; i += 256) {
        float v;
        if (i < 64)       v = x[i];
        else if (i < 128) v = po[i - 64];
        else              v = st[i - 128];
        s_in[i] = v;
    }
    __syncthreads();

    const int wave = t >> 6;
    const int lane = t & 63;
    const int r = blockIdx.x * 4 + wave;   // r in [0,1024)

    const float* wr = w + (size_t)r * 384;
    float acc = 0.f;
    {   // first 256 floats via float4
        const int idx = lane * 4;
        float4 wv = *reinterpret_cast<const float4*>(wr + idx);
        float4 iv = *reinterpret_cast<const float4*>(s_in + idx);
        acc += wv.x * iv.x + wv.y * iv.y + wv.z * iv.z + wv.w * iv.w;
    }
    {   // remaining 128 floats via float2
        const int idx = 256 + lane * 2;
        float2 wv = *reinterpret_cast<const float2*>(wr + idx);
        float2 iv = *reinterpret_cast<const float2*>(s_in + idx);
        acc += wv.x * iv.x + wv.y * iv.y;
    }
    acc = wave_reduce_sum(acc);
    if (lane == 0) out[r] = fmaxf(acc + b[r], 0.f);
}

// Generic layer: K = 1024 input dim, one row per wave.
// rows=1024 -> 256 blocks; rows=64 -> 16 blocks.
__global__ void __launch_bounds__(256) fc_relu_1024(
        const float* __restrict__ w, const float* __restrict__ b,
        const float* __restrict__ in, float* __restrict__ out, int rows) {
    __shared__ float s_in[1024];
    const int t = threadIdx.x;
    for (int i = t; i < 1024; i += 256) s_in[i] = in[i];
    __syncthreads();

    const int wave = t >> 6;
    const int lane = t & 63;
    const int r = blockIdx.x * 4 + wave;
    if (r >= rows) return;

    const float* wr = w + (size_t)r * 1024;
    float acc = 0.f;
#pragma unroll
    for (int it = 0; it < 4; ++it) {   // 4 * 256 floats
        const int idx = it * 256 + lane * 4;
        float4 wv = *reinterpret_cast<const float4*>(wr + idx);
        float4 iv = *reinterpret_cast<const float4*>(s_in + idx);
        acc += wv.x * iv.x + wv.y * iv.y + wv.z * iv.z + wv.w * iv.w;
    }
    acc = wave_reduce_sum(acc);
    if (lane == 0) out[r] = fmaxf(acc + b[r], 0.f);
}

extern "C" void kernel_launch(void* const* d_in, const int* in_sizes, int n_in,
                              void* d_out, int out_size, void* d_ws, size_t ws_size,
                              hipStream_t stream) {
    // setup_inputs() dict order:
    // 0:x 1:w1_0 2:b1_0 3:w1_1 4:b1_1 5:w1_2 6:b1_2
    // 7..16: w2_*/b2_*  17..26: w3_*/b3_*
    // 27: prev_output 28: state 29: prev_weight_change 30: prev_bias_change
    const float* x    = (const float*)d_in[0];
    const float* w1_0 = (const float*)d_in[1];
    const float* b1_0 = (const float*)d_in[2];
    const float* w1_1 = (const float*)d_in[3];
    const float* b1_1 = (const float*)d_in[4];
    const float* w1_2 = (const float*)d_in[5];
    const float* b1_2 = (const float*)d_in[6];
    const float* po   = (const float*)d_in[27];
    const float* st   = (const float*)d_in[28];

    float* out = (float*)d_out;          // 64 floats
    float* h1 = (float*)d_ws;            // 1024 floats
    float* h2 = h1 + 1024;               // 1024 floats

    fc_relu_concat<<<256, 256, 0, stream>>>(x, po, st, w1_0, b1_0, h1);
    fc_relu_1024<<<256, 256, 0, stream>>>(w1_1, b1_1, h1, h2, 1024);
    fc_relu_1024<<<16, 256, 0, stream>>>(w1_2, b1_2, h2, out, 64);
}